// Round 6
// baseline (237.739 us; speedup 1.0000x reference)
//
#include <hip/hip_runtime.h>

// Problem: N=65536 rows, C=100 classes, 6 matrices (outputs1..5, mimic).
// out[0]            = max over ALL elements of outputs1..5
// out[1 + row*6 + j]= softmax_j(margins(row)/TEMP), TEMP=2
// margin(x,t) = (x[t] == max(x)) ? max(x) - second_max(x) : 0
//
// R5 post-mortem: thread-per-row global loads are scatter-bound (64 distinct
// lines per wave-load) -> ~1.7 TB/s ceiling regardless of occupancy (R4 10%
// vs R5 40% occupancy: 1.1 -> 1.3 TB/s only). This version: each 64-thread
// block stages a 64-row x 100-col tile with 25 perfectly CONTIGUOUS dwordx4
// wave-loads into LDS (odd row stride 101 -> conflict-free b32 readback),
// then thread-per-row reduction out of LDS. Global side is pure streaming.

constexpr int C = 100;
constexpr int ROWS = 64;            // rows per block tile
constexpr int LDS_STRIDE = 101;     // odd stride: readback banks 2-way (free)
constexpr float INV_TEMP = 0.5f;    // 1/TEMP

// Order-preserving float -> unsigned encoding for atomicMax.
// Every float encodes to >= 0x007FFFFF (= enc(-inf)) > 0, so memset-0 is a
// valid identity for max.
__device__ __forceinline__ unsigned enc_f(float f) {
    unsigned u = __float_as_uint(f);
    return (u & 0x80000000u) ? ~u : (u | 0x80000000u);
}

// Grid: (ceil(n/64), 6). Block: 64 threads (1 wave).
__global__ __launch_bounds__(64) void margin_kernel(
    const float* __restrict__ o1, const float* __restrict__ o2,
    const float* __restrict__ o3, const float* __restrict__ o4,
    const float* __restrict__ o5, const float* __restrict__ mimic,
    const int* __restrict__ tgt, float* __restrict__ out,
    unsigned* __restrict__ ws, int n)
{
    __shared__ float lds[ROWS * LDS_STRIDE];   // 25.9 KB -> 6 blocks/CU

    const int lane = threadIdx.x;              // 0..63
    const int m    = blockIdx.y;               // 0..5 (uniform)
    const int row0 = blockIdx.x * ROWS;

    const float* __restrict__ mat =
        (m == 0) ? o1 : (m == 1) ? o2 : (m == 2) ? o3 :
        (m == 3) ? o4 : (m == 4) ? o5 : mimic;

    // int32-vs-int64 target layout detection (wave-uniform).
    // int64 little-endian nonneg => odd 32-bit words all zero.
    const int pidx  = 2 * lane + 1;
    const int probe = (pidx < n) ? tgt[pidx] : 0;
    const unsigned long long nz = __ballot(probe != 0);
    const int tstride = (nz == 0ull) ? 2 : 1;

    // ---- Stage tile: 64 rows x 100 floats = 1600 float4, fully contiguous.
    const float4* __restrict__ src4 = (const float4*)(mat + (size_t)row0 * C);
    const bool full = (row0 + ROWS <= n);
    #pragma unroll
    for (int i = 0; i < (ROWS * C) / (4 * 64); ++i) {   // 25 iters
        const int c = i * 64 + lane;        // contiguous float4 index
        const int r = c / 25;               // 25 float4 per row
        const int f = c - r * 25;
        float4 v = make_float4(0.f, 0.f, 0.f, 0.f);
        if (full || row0 + r < n) v = src4[c];
        const int o = r * LDS_STRIDE + f * 4;
        lds[o]     = v.x;
        lds[o + 1] = v.y;
        lds[o + 2] = v.z;
        lds[o + 3] = v.w;
    }
    __syncthreads();

    // ---- Thread-per-row reduce from LDS (banks: stride 101 is odd -> free).
    float gmax = -INFINITY;
    const int row = row0 + lane;
    if (row < n) {
        const int t = tgt[(size_t)row * tstride];   // 0..99
        const float* __restrict__ p = lds + lane * LDS_STRIDE;
        // two independent top-2 trackers (halve the fmax dependence chain)
        float m1a = -INFINITY, m2a = -INFINITY;
        float m1b = -INFINITY, m2b = -INFINITY;
        #pragma unroll
        for (int j = 0; j < C / 2; ++j) {
            const float a = p[j];
            const float b = p[j + C / 2];
            m2a = fmaxf(m2a, fminf(m1a, a)); m1a = fmaxf(m1a, a);
            m2b = fmaxf(m2b, fminf(m1b, b)); m1b = fmaxf(m1b, b);
        }
        const float m1 = fmaxf(m1a, m1b);
        const float m2 = fmaxf(fminf(m1a, m1b), fmaxf(m2a, m2b));
        const float tv = p[t];
        out[1 + (size_t)row * 6 + m] = (tv == m1) ? (m1 - m2) * INV_TEMP : 0.0f;
        if (m < 5) gmax = m1;               // mimic excluded from max_preds
    }

    // per-wave max, one atomic per block (only matrices 0..4)
    #pragma unroll
    for (int s = 1; s < 64; s <<= 1) gmax = fmaxf(gmax, __shfl_xor(gmax, s));
    if (lane == 0 && m < 5) atomicMax(ws, enc_f(gmax));
}

// In-place 6-wide softmax over out[1+row*6 .. +5]; thread 0 decodes out[0].
__global__ __launch_bounds__(256) void softmax_kernel(
    float* __restrict__ out, const unsigned* __restrict__ ws, int n)
{
    const int row = blockIdx.x * blockDim.x + threadIdx.x;
    if (row < n) {
        float* p = out + 1 + (size_t)row * 6;
        float mrg[6];
        #pragma unroll
        for (int j = 0; j < 6; ++j) mrg[j] = p[j];
        float mx = mrg[0];
        #pragma unroll
        for (int j = 1; j < 6; ++j) mx = fmaxf(mx, mrg[j]);
        float e[6], s = 0.0f;
        #pragma unroll
        for (int j = 0; j < 6; ++j) { e[j] = __expf(mrg[j] - mx); s += e[j]; }
        const float inv = 1.0f / s;
        #pragma unroll
        for (int j = 0; j < 6; ++j) p[j] = e[j] * inv;
    }
    if (row == 0) {
        const unsigned e = ws[0];
        const unsigned bits = (e & 0x80000000u) ? (e & 0x7FFFFFFFu) : ~e;
        out[0] = __uint_as_float(bits);
    }
}

extern "C" void kernel_launch(void* const* d_in, const int* in_sizes, int n_in,
                              void* d_out, int out_size, void* d_ws, size_t ws_size,
                              hipStream_t stream) {
    const float* o1    = (const float*)d_in[0];
    const float* o2    = (const float*)d_in[1];
    const float* o3    = (const float*)d_in[2];
    const float* o4    = (const float*)d_in[3];
    const float* o5    = (const float*)d_in[4];
    const float* mimic = (const float*)d_in[5];
    const int*   tgt   = (const int*)d_in[6];
    float*       out   = (float*)d_out;
    unsigned*    ws    = (unsigned*)d_ws;

    const int n = in_sizes[6];   // N = 65536

    // ws[0] = encoded running max; 0 is the identity for the encoding.
    hipMemsetAsync(ws, 0, sizeof(unsigned), stream);

    dim3 grid((n + ROWS - 1) / ROWS, 6);   // 1024 x 6 = 6144 one-wave blocks
    margin_kernel<<<grid, 64, 0, stream>>>(o1, o2, o3, o4, o5, mimic,
                                           tgt, out, ws, n);
    softmax_kernel<<<(n + 255) / 256, 256, 0, stream>>>(out, ws, n);
}

// Round 7
// 209.035 us; speedup vs baseline: 1.1373x; 1.1373x over previous
//
#include <hip/hip_runtime.h>

// Problem: N=65536 rows, C=100 classes, 6 matrices (outputs1..5, mimic).
// out[0]            = max over ALL elements of outputs1..5
// out[1 + row*6 + j]= softmax_j(margins(row)/TEMP), TEMP=2
// margin(x,t) = (x[t] == max(x)) ? max(x) - second_max(x) : 0
//
// R6 post-mortem: padding (stride 101) + scalar b32 LDS writes CREATED the
// 2.8M bank conflicts, and the VGPR round-trip staging serialized on global
// latency. Fix: linear (unpadded) float4 LDS layout is conflict-free on BOTH
// sides at b128 granularity (readback group = (lane+i) mod 8 -> exactly 8
// lanes/group = the b128 floor), and global_load_lds dwordx4 streams each
// 64-row tile as 25 contiguous 1KB transactions with no VGPR round-trip.

constexpr int C = 100;
constexpr int ROWS = 64;                        // rows per tile = one wave
constexpr int F4_PER_ROW = 25;                  // 100 floats = 25 float4
constexpr int F4_PER_TILE = ROWS * F4_PER_ROW;  // 1600 float4 = 25.6 KB
constexpr float INV_TEMP = 0.5f;                // 1/TEMP

typedef __attribute__((address_space(3))) void       as3_void;
typedef const __attribute__((address_space(1))) void as1_void;

// Order-preserving float -> unsigned encoding for atomicMax.
// enc(f) >= enc(-inf) = 0x007FFFFF > 0, so memset-0 is a valid identity.
__device__ __forceinline__ unsigned enc_f(float f) {
    unsigned u = __float_as_uint(f);
    return (u & 0x80000000u) ? ~u : (u | 0x80000000u);
}

// Grid: (n/64, 6). Block: 64 threads (1 wave). LDS 25.6KB -> 6 blocks/CU.
__global__ __launch_bounds__(64) void margin_kernel(
    const float* __restrict__ o1, const float* __restrict__ o2,
    const float* __restrict__ o3, const float* __restrict__ o4,
    const float* __restrict__ o5, const float* __restrict__ mimic,
    const int* __restrict__ tgt, float* __restrict__ out,
    unsigned* __restrict__ ws, int n)
{
    __shared__ float4 tile[F4_PER_TILE];   // linear, NO padding

    const int lane = threadIdx.x;          // 0..63
    const int m    = blockIdx.y;           // 0..5 (uniform)
    const int row0 = blockIdx.x * ROWS;

    const float* __restrict__ mat =
        (m == 0) ? o1 : (m == 1) ? o2 : (m == 2) ? o3 :
        (m == 3) ? o4 : (m == 4) ? o5 : mimic;

    // int32-vs-int64 target layout detection (wave-uniform).
    // int64 little-endian nonneg => odd 32-bit words all zero.
    const int pidx  = 2 * lane + 1;
    const int probe = (pidx < n) ? tgt[pidx] : 0;
    const unsigned long long nz = __ballot(probe != 0);
    const int tstride = (nz == 0ull) ? 2 : 1;

    // ---- Stage tile: 25 contiguous 1KB global->LDS DMA ops (dwordx4).
    // LDS dest of each op is wave-uniform base + lane*16 -> slot k*64+lane
    // holds global float4 (row0*25 + k*64 + lane): exactly linear order.
    const float4* __restrict__ src4 =
        (const float4*)mat + (size_t)row0 * F4_PER_ROW;
    const int f4_valid = (n - row0) * F4_PER_ROW;   // float4s in this tile
    #pragma unroll
    for (int k = 0; k < F4_PER_ROW; ++k) {
        const int c = k * 64 + lane;
        if (c < f4_valid) {
            __builtin_amdgcn_global_load_lds((as1_void*)(src4 + c),
                                             (as3_void*)(tile + k * 64),
                                             16, 0, 0);
        }
    }
    __builtin_amdgcn_s_waitcnt(0);   // drain vmcnt (DMA completion)
    __syncthreads();

    // ---- Thread-per-row reduce from LDS. b128 reads, conflict-free:
    // slot = lane*25 + i -> bank-group (lane+i) mod 8, 8 lanes each.
    float gmax = -INFINITY;
    const int row = row0 + lane;
    if (row < n) {
        const float4* __restrict__ p = tile + lane * F4_PER_ROW;
        // 4 independent top-2 trackers (ILP on the fmax chains)
        float m1x = -INFINITY, m2x = -INFINITY;
        float m1y = -INFINITY, m2y = -INFINITY;
        float m1z = -INFINITY, m2z = -INFINITY;
        float m1w = -INFINITY, m2w = -INFINITY;
        #pragma unroll
        for (int i = 0; i < F4_PER_ROW; ++i) {
            const float4 v = p[i];
            m2x = fmaxf(m2x, fminf(m1x, v.x)); m1x = fmaxf(m1x, v.x);
            m2y = fmaxf(m2y, fminf(m1y, v.y)); m1y = fmaxf(m1y, v.y);
            m2z = fmaxf(m2z, fminf(m1z, v.z)); m1z = fmaxf(m1z, v.z);
            m2w = fmaxf(m2w, fminf(m1w, v.w)); m1w = fmaxf(m1w, v.w);
        }
        // merge 4 trackers -> (m1, m2)
        const float m1xy = fmaxf(m1x, m1y);
        const float m2xy = fmaxf(fminf(m1x, m1y), fmaxf(m2x, m2y));
        const float m1zw = fmaxf(m1z, m1w);
        const float m2zw = fmaxf(fminf(m1z, m1w), fmaxf(m2z, m2w));
        const float m1   = fmaxf(m1xy, m1zw);
        const float m2   = fmaxf(fminf(m1xy, m1zw), fmaxf(m2xy, m2zw));

        const int   t  = tgt[(size_t)row * tstride];          // 0..99
        const float tv = ((const float*)p)[t];                // 1 ds_read_b32
        out[1 + (size_t)row * 6 + m] = (tv == m1) ? (m1 - m2) * INV_TEMP : 0.0f;
        if (m < 5) gmax = m1;               // mimic excluded from max_preds
    }

    // per-wave max, one atomic per block (only matrices 0..4)
    if (m < 5) {
        #pragma unroll
        for (int s = 1; s < 64; s <<= 1) gmax = fmaxf(gmax, __shfl_xor(gmax, s));
        if (lane == 0) atomicMax(ws, enc_f(gmax));
    }
}

// In-place 6-wide softmax over out[1+row*6 .. +5]; thread 0 decodes out[0].
__global__ __launch_bounds__(256) void softmax_kernel(
    float* __restrict__ out, const unsigned* __restrict__ ws, int n)
{
    const int row = blockIdx.x * blockDim.x + threadIdx.x;
    if (row < n) {
        float* p = out + 1 + (size_t)row * 6;
        float mrg[6];
        #pragma unroll
        for (int j = 0; j < 6; ++j) mrg[j] = p[j];
        float mx = mrg[0];
        #pragma unroll
        for (int j = 1; j < 6; ++j) mx = fmaxf(mx, mrg[j]);
        float e[6], s = 0.0f;
        #pragma unroll
        for (int j = 0; j < 6; ++j) { e[j] = __expf(mrg[j] - mx); s += e[j]; }
        const float inv = 1.0f / s;
        #pragma unroll
        for (int j = 0; j < 6; ++j) p[j] = e[j] * inv;
    }
    if (row == 0) {
        const unsigned e = ws[0];
        const unsigned bits = (e & 0x80000000u) ? (e & 0x7FFFFFFFu) : ~e;
        out[0] = __uint_as_float(bits);
    }
}

extern "C" void kernel_launch(void* const* d_in, const int* in_sizes, int n_in,
                              void* d_out, int out_size, void* d_ws, size_t ws_size,
                              hipStream_t stream) {
    const float* o1    = (const float*)d_in[0];
    const float* o2    = (const float*)d_in[1];
    const float* o3    = (const float*)d_in[2];
    const float* o4    = (const float*)d_in[3];
    const float* o5    = (const float*)d_in[4];
    const float* mimic = (const float*)d_in[5];
    const int*   tgt   = (const int*)d_in[6];
    float*       out   = (float*)d_out;
    unsigned*    ws    = (unsigned*)d_ws;

    const int n = in_sizes[6];   // N = 65536

    // ws[0] = encoded running max; 0 is the identity for the encoding.
    hipMemsetAsync(ws, 0, sizeof(unsigned), stream);

    dim3 grid((n + ROWS - 1) / ROWS, 6);   // 1024 x 6 one-wave blocks
    margin_kernel<<<grid, 64, 0, stream>>>(o1, o2, o3, o4, o5, mimic,
                                           tgt, out, ws, n);
    softmax_kernel<<<(n + 255) / 256, 256, 0, stream>>>(out, ws, n);
}

// Round 8
// 186.644 us; speedup vs baseline: 1.2738x; 1.1200x over previous
//
#include <hip/hip_runtime.h>

// Problem: N=65536 rows, C=100 classes, 6 matrices (outputs1..5, mimic).
// out[0]            = max over ALL elements of outputs1..5
// out[1 + row*6 + j]= softmax_j(margins(row)/TEMP), TEMP=2
// margin(x,t) = (x[t] == max(x)) ? max(x) - second_max(x) : 0
//
// R7 post-mortem: R4 (4 waves/CU scatter)=78.5us, R5 (13 waves scatter)=88.6,
// R7 (6 waves DMA-streamed)=89.5 -- all ~1.7-2.0 TB/s logical, all pipes idle
// (VALU<6%, HBM<15%, conflicts ~0). Latency/MLP-bound in every tested config.
// This version tests the untested regime: FULL occupancy. Row split across 2
// partner threads (13/12 float4, overlap-free), thread-per-(half-row,matrix)
// = 12288 waves = 48/CU demanded -> 32/CU resident (hw cap). Partner top-2
// merge via one shfl_xor(1); one atomic per 256-thr block.

constexpr int C = 100;
constexpr float INV_TEMP = 0.5f;   // 1/TEMP

// Order-preserving float -> unsigned encoding for atomicMax.
// enc(f) >= enc(-inf) = 0x007FFFFF > 0, so memset-0 is a valid identity.
__device__ __forceinline__ unsigned enc_f(float f) {
    unsigned u = __float_as_uint(f);
    return (u & 0x80000000u) ? ~u : (u | 0x80000000u);
}

// Grid: (ceil(2n/256), 6). Block: 256 threads. Thread = (row, half, matrix).
__global__ __launch_bounds__(256) void margin_kernel(
    const float* __restrict__ o1, const float* __restrict__ o2,
    const float* __restrict__ o3, const float* __restrict__ o4,
    const float* __restrict__ o5, const float* __restrict__ mimic,
    const int* __restrict__ tgt, float* __restrict__ out,
    unsigned* __restrict__ ws, int n)
{
    __shared__ unsigned wmax[4];

    const int m    = blockIdx.y;                       // 0..5 (uniform)
    const int tid2 = blockIdx.x * 256 + threadIdx.x;
    const int row  = tid2 >> 1;                        // partner pair = lanes 2k,2k+1
    const int half = tid2 & 1;                         // 0: f4[0,13), 1: f4[13,25)
    const int lane = threadIdx.x & 63;

    const float* __restrict__ mat =
        (m == 0) ? o1 : (m == 1) ? o2 : (m == 2) ? o3 :
        (m == 3) ? o4 : (m == 4) ? o5 : mimic;

    // int32-vs-int64 target layout detection (wave-uniform).
    // int64 little-endian nonneg => odd 32-bit words all zero.
    const int pidx  = 2 * lane + 1;
    const int probe = (pidx < n) ? tgt[pidx] : 0;
    const unsigned long long nz = __ballot(probe != 0);
    const int tstride = (nz == 0ull) ? 2 : 1;

    float rowM1 = -INFINITY;   // post-merge row max (for global max reduce)

    if (row < n) {             // partner lanes agree on this predicate
        const size_t rowoff = (size_t)row * C;
        const float4* __restrict__ p4 =
            (const float4*)(mat + rowoff) + (half ? 13 : 0);

        // 4 independent top-2 trackers (ILP on the fmax chains)
        float m1x = -INFINITY, m2x = -INFINITY;
        float m1y = -INFINITY, m2y = -INFINITY;
        float m1z = -INFINITY, m2z = -INFINITY;
        float m1w = -INFINITY, m2w = -INFINITY;
        #pragma unroll
        for (int i = 0; i < 12; ++i) {   // both halves: 12 f4s
            const float4 v = p4[i];
            m2x = fmaxf(m2x, fminf(m1x, v.x)); m1x = fmaxf(m1x, v.x);
            m2y = fmaxf(m2y, fminf(m1y, v.y)); m1y = fmaxf(m1y, v.y);
            m2z = fmaxf(m2z, fminf(m1z, v.z)); m1z = fmaxf(m1z, v.z);
            m2w = fmaxf(m2w, fminf(m1w, v.w)); m1w = fmaxf(m1w, v.w);
        }
        if (!half) {                     // half 0 owns the 13th f4 (index 12)
            const float4 v = p4[12];
            m2x = fmaxf(m2x, fminf(m1x, v.x)); m1x = fmaxf(m1x, v.x);
            m2y = fmaxf(m2y, fminf(m1y, v.y)); m1y = fmaxf(m1y, v.y);
            m2z = fmaxf(m2z, fminf(m1z, v.z)); m1z = fmaxf(m1z, v.z);
            m2w = fmaxf(m2w, fminf(m1w, v.w)); m1w = fmaxf(m1w, v.w);
        }
        // merge 4 trackers -> this thread's (tm1, tm2)
        const float m1xy = fmaxf(m1x, m1y);
        const float m2xy = fmaxf(fminf(m1x, m1y), fmaxf(m2x, m2y));
        const float m1zw = fmaxf(m1z, m1w);
        const float m2zw = fmaxf(fminf(m1z, m1w), fmaxf(m2z, m2w));
        const float tm1  = fmaxf(m1xy, m1zw);
        const float tm2  = fmaxf(fminf(m1xy, m1zw), fmaxf(m2xy, m2zw));

        // merge with partner (lane^1; halves are disjoint -> exact)
        const float p1 = __shfl_xor(tm1, 1);
        const float p2 = __shfl_xor(tm2, 1);
        const float M1 = fmaxf(tm1, p1);
        const float M2 = fmaxf(fminf(tm1, p1), fmaxf(tm2, p2));

        const int   t  = tgt[(size_t)row * tstride];   // 0..99 (both partners)
        const float tv = mat[rowoff + t];              // L1-hit, same value both
        if (!half)
            out[1 + (size_t)row * 6 + m] = (tv == M1) ? (M1 - M2) * INV_TEMP : 0.0f;
        rowM1 = M1;
    }

    // global max over matrices 0..4: wave reduce, 4-slot LDS, 1 atomic/block
    #pragma unroll
    for (int s = 1; s < 64; s <<= 1) rowM1 = fmaxf(rowM1, __shfl_xor(rowM1, s));
    if (m < 5) {                                  // block-uniform branch
        if (lane == 0) wmax[threadIdx.x >> 6] = enc_f(rowM1);
        __syncthreads();
        if (threadIdx.x == 0) {
            const unsigned u = max(max(wmax[0], wmax[1]), max(wmax[2], wmax[3]));
            atomicMax(ws, u);
        }
    }
}

// In-place 6-wide softmax over out[1+row*6 .. +5]; thread 0 decodes out[0].
__global__ __launch_bounds__(256) void softmax_kernel(
    float* __restrict__ out, const unsigned* __restrict__ ws, int n)
{
    const int row = blockIdx.x * blockDim.x + threadIdx.x;
    if (row < n) {
        float* p = out + 1 + (size_t)row * 6;
        float mrg[6];
        #pragma unroll
        for (int j = 0; j < 6; ++j) mrg[j] = p[j];
        float mx = mrg[0];
        #pragma unroll
        for (int j = 1; j < 6; ++j) mx = fmaxf(mx, mrg[j]);
        float e[6], s = 0.0f;
        #pragma unroll
        for (int j = 0; j < 6; ++j) { e[j] = __expf(mrg[j] - mx); s += e[j]; }
        const float inv = 1.0f / s;
        #pragma unroll
        for (int j = 0; j < 6; ++j) p[j] = e[j] * inv;
    }
    if (row == 0) {
        const unsigned e = ws[0];
        const unsigned bits = (e & 0x80000000u) ? (e & 0x7FFFFFFFu) : ~e;
        out[0] = __uint_as_float(bits);
    }
}

extern "C" void kernel_launch(void* const* d_in, const int* in_sizes, int n_in,
                              void* d_out, int out_size, void* d_ws, size_t ws_size,
                              hipStream_t stream) {
    const float* o1    = (const float*)d_in[0];
    const float* o2    = (const float*)d_in[1];
    const float* o3    = (const float*)d_in[2];
    const float* o4    = (const float*)d_in[3];
    const float* o5    = (const float*)d_in[4];
    const float* mimic = (const float*)d_in[5];
    const int*   tgt   = (const int*)d_in[6];
    float*       out   = (float*)d_out;
    unsigned*    ws    = (unsigned*)d_ws;

    const int n = in_sizes[6];   // N = 65536

    // ws[0] = encoded running max; 0 is the identity for the encoding.
    hipMemsetAsync(ws, 0, sizeof(unsigned), stream);

    dim3 grid((2 * n + 255) / 256, 6);   // 512 x 6 = 3072 blocks, 12288 waves
    margin_kernel<<<grid, 256, 0, stream>>>(o1, o2, o3, o4, o5, mimic,
                                            tgt, out, ws, n);
    softmax_kernel<<<(n + 255) / 256, 256, 0, stream>>>(out, ws, n);
}